// Round 1
// baseline (1596.783 us; speedup 1.0000x reference)
//
#include <hip/hip_runtime.h>

#define N_NODES 50000
#define E_EDGES 1600000
#define HC 128
#define NEG_SLOPE 0.2f
#define SM_EPS 1e-16f

// ---------------- K0: wvec = v_mapping.T @ l2norm(att) ----------------
__global__ __launch_bounds__(256) void k0_wvec(
    const float* __restrict__ v_mapping,  // [64,256]
    const float* __restrict__ att_src,    // [64]
    const float* __restrict__ att_dst,    // [64]
    float* __restrict__ wvec_src, float* __restrict__ wvec_dst) {
  int j = threadIdx.x;  // 0..255
  float ns = 0.f, nd = 0.f;
  for (int f = 0; f < 64; ++f) {
    float a = att_src[f]; ns = fmaf(a, a, ns);
    float b = att_dst[f]; nd = fmaf(b, b, nd);
  }
  ns = fmaxf(sqrtf(ns), 1e-12f);
  nd = fmaxf(sqrtf(nd), 1e-12f);
  float ws_ = 0.f, wd_ = 0.f;
  for (int f = 0; f < 64; ++f) {
    float v = v_mapping[f * 256 + j];
    ws_ = fmaf(v, att_src[f], ws_);
    wd_ = fmaf(v, att_dst[f], wd_);
  }
  wvec_src[j] = ws_ / ns;
  wvec_dst[j] = wd_ / nd;
}

// ---------------- K1: node phase ----------------
// 2 rows per 256-thread block. x_proj, out=x_proj+bias, a_src/a_dst dots, denom=0.
__global__ __launch_bounds__(256) void k1_node(
    const float* __restrict__ x,      // [N,256]
    const float* __restrict__ W,      // [256,128]
    const float* __restrict__ bias,   // [128]
    const float* __restrict__ wvec_src, const float* __restrict__ wvec_dst,
    float* __restrict__ x_proj,       // [N,128]
    float* __restrict__ out,          // [N,128]
    float* __restrict__ a_src, float* __restrict__ a_dst,
    float* __restrict__ denom) {
  __shared__ float xs[2][256];
  const int rowbase = blockIdx.x * 2;
  const int tid = threadIdx.x;

  // load 2 rows (512 floats) with float2 per thread
  const float2* xsrc = (const float2*)(x + rowbase * 256);
  ((float2*)&xs[0][0])[tid] = xsrc[tid];
  __syncthreads();

  const int r = tid >> 7;        // 0/1
  const int ch = tid & 127;
  const int row = rowbase + r;

  float acc = 0.f;
#pragma unroll 8
  for (int k = 0; k < 256; ++k) acc = fmaf(xs[r][k], W[k * HC + ch], acc);
  x_proj[row * HC + ch] = acc;
  out[row * HC + ch] = acc + bias[ch];

  // attention scalar dots: wave w: (row = w>>1, src/dst = w&1)
  const int wid = tid >> 6, lane = tid & 63;
  const int rr = wid >> 1;
  const float* wv = (wid & 1) ? wvec_dst : wvec_src;
  float d = 0.f;
#pragma unroll
  for (int k = lane; k < 256; k += 64) d = fmaf(xs[rr][k], wv[k], d);
  for (int off = 32; off > 0; off >>= 1) d += __shfl_down(d, off);
  if (lane == 0) {
    if (wid & 1) a_dst[rowbase + rr] = d;
    else { a_src[rowbase + rr] = d; denom[rowbase + rr] = 0.f; }
  }
}

// ---------------- K2: edge pass 1 (exp + denom) ----------------
__global__ __launch_bounds__(256) void k2_edge1(
    const int* __restrict__ ei,      // [2,E] flat
    const float* __restrict__ a_src, const float* __restrict__ a_dst,
    float* __restrict__ e_val, float* __restrict__ denom) {
  int e = blockIdx.x * 256 + threadIdx.x;
  if (e >= E_EDGES) return;
  int s = ei[e];
  int d = ei[E_EDGES + e];
  float a = a_src[s] + a_dst[d];
  a = a > 0.f ? a : NEG_SLOPE * a;
  float ev = __expf(a);
  e_val[e] = ev;
  unsafeAtomicAdd(&denom[d], ev);
}

// ---------------- K3: edge pass 2 (weighted scatter-add) ----------------
// one wave per edge; lane handles 2 channels (float2 gather, 2 f32 atomics)
__global__ __launch_bounds__(256) void k3_scatter(
    const int* __restrict__ ei,
    const float* __restrict__ e_val, const float* __restrict__ denom,
    const float* __restrict__ x_proj, float* __restrict__ out) {
  const int wib = threadIdx.x >> 6;
  const int lane = threadIdx.x & 63;
  const int e = blockIdx.x * 4 + wib;
  if (e >= E_EDGES) return;
  const int s = ei[e];
  const int d = ei[E_EDGES + e];
  const float alpha = e_val[e] / (denom[d] + SM_EPS);
  const float2 v = ((const float2*)(x_proj + (size_t)s * HC))[lane];
  float* op = out + (size_t)d * HC + 2 * lane;
  unsafeAtomicAdd(op, alpha * v.x);
  unsafeAtomicAdd(op + 1, alpha * v.y);
}

extern "C" void kernel_launch(void* const* d_in, const int* in_sizes, int n_in,
                              void* d_out, int out_size, void* d_ws, size_t ws_size,
                              hipStream_t stream) {
  const float* x         = (const float*)d_in[0];
  const int*   ei        = (const int*)d_in[1];
  const float* v_mapping = (const float*)d_in[2];
  const float* W_src     = (const float*)d_in[3];
  const float* att_src   = (const float*)d_in[4];
  const float* att_dst   = (const float*)d_in[5];
  const float* bias      = (const float*)d_in[6];
  float* out = (float*)d_out;

  // workspace layout
  char* ws = (char*)d_ws;
  float* x_proj   = (float*)ws;                      ws += (size_t)N_NODES * HC * 4;
  float* a_src    = (float*)ws;                      ws += (size_t)N_NODES * 4;
  float* a_dst    = (float*)ws;                      ws += (size_t)N_NODES * 4;
  float* denom    = (float*)ws;                      ws += (size_t)N_NODES * 4;
  float* wvec_src = (float*)ws;                      ws += 256 * 4;
  float* wvec_dst = (float*)ws;                      ws += 256 * 4;
  float* e_val    = (float*)ws;                      ws += (size_t)E_EDGES * 4;

  k0_wvec<<<1, 256, 0, stream>>>(v_mapping, att_src, att_dst, wvec_src, wvec_dst);
  k1_node<<<N_NODES / 2, 256, 0, stream>>>(x, W_src, bias, wvec_src, wvec_dst,
                                           x_proj, out, a_src, a_dst, denom);
  k2_edge1<<<(E_EDGES + 255) / 256, 256, 0, stream>>>(ei, a_src, a_dst, e_val, denom);
  k3_scatter<<<E_EDGES / 4, 256, 0, stream>>>(ei, e_val, denom, x_proj, out);
}

// Round 2
// 581.423 us; speedup vs baseline: 2.7463x; 2.7463x over previous
//
#include <hip/hip_runtime.h>

#define N_NODES 50000
#define E_EDGES 1600000
#define HC 128
#define NEG_SLOPE 0.2f
#define SM_EPS 1e-16f

// ---------------- K0: wvec = v_mapping.T @ l2norm(att) ----------------
__global__ __launch_bounds__(256) void k0_wvec(
    const float* __restrict__ v_mapping,  // [64,256]
    const float* __restrict__ att_src,    // [64]
    const float* __restrict__ att_dst,    // [64]
    float* __restrict__ wvec_src, float* __restrict__ wvec_dst) {
  int j = threadIdx.x;  // 0..255
  float ns = 0.f, nd = 0.f;
  for (int f = 0; f < 64; ++f) {
    float a = att_src[f]; ns = fmaf(a, a, ns);
    float b = att_dst[f]; nd = fmaf(b, b, nd);
  }
  ns = fmaxf(sqrtf(ns), 1e-12f);
  nd = fmaxf(sqrtf(nd), 1e-12f);
  float ws_ = 0.f, wd_ = 0.f;
  for (int f = 0; f < 64; ++f) {
    float v = v_mapping[f * 256 + j];
    ws_ = fmaf(v, att_src[f], ws_);
    wd_ = fmaf(v, att_dst[f], wd_);
  }
  wvec_src[j] = ws_ / ns;
  wvec_dst[j] = wd_ / nd;
}

// ---------------- K1: node phase ----------------
__global__ __launch_bounds__(256) void k1_node(
    const float* __restrict__ x,      // [N,256]
    const float* __restrict__ W,      // [256,128]
    const float* __restrict__ bias,   // [128]
    const float* __restrict__ wvec_src, const float* __restrict__ wvec_dst,
    float* __restrict__ x_proj,       // [N,128]
    float* __restrict__ out,          // [N,128]
    float* __restrict__ a_src, float* __restrict__ a_dst) {
  __shared__ float xs[2][256];
  const int rowbase = blockIdx.x * 2;
  const int tid = threadIdx.x;

  const float2* xsrc = (const float2*)(x + rowbase * 256);
  ((float2*)&xs[0][0])[tid] = xsrc[tid];
  __syncthreads();

  const int r = tid >> 7;        // 0/1
  const int ch = tid & 127;
  const int row = rowbase + r;

  float acc = 0.f;
#pragma unroll 8
  for (int k = 0; k < 256; ++k) acc = fmaf(xs[r][k], W[k * HC + ch], acc);
  x_proj[row * HC + ch] = acc;
  out[row * HC + ch] = acc + bias[ch];

  const int wid = tid >> 6, lane = tid & 63;
  const int rr = wid >> 1;
  const float* wv = (wid & 1) ? wvec_dst : wvec_src;
  float d = 0.f;
#pragma unroll
  for (int k = lane; k < 256; k += 64) d = fmaf(xs[rr][k], wv[k], d);
  for (int off = 32; off > 0; off >>= 1) d += __shfl_down(d, off);
  if (lane == 0) {
    if (wid & 1) a_dst[rowbase + rr] = d;
    else a_src[rowbase + rr] = d;
  }
}

// ---------------- KZ: zero counts + cursors ----------------
__global__ __launch_bounds__(256) void kz_zero(int* __restrict__ counts,
                                               int* __restrict__ cursor) {
  int i = blockIdx.x * 256 + threadIdx.x;
  if (i < N_NODES) { counts[i] = 0; cursor[i] = 0; }
}

// ---------------- KB: dst histogram ----------------
__global__ __launch_bounds__(256) void kb_hist(const int* __restrict__ ei,
                                               int* __restrict__ counts) {
  int e = blockIdx.x * 256 + threadIdx.x;
  int d = ei[E_EDGES + e];
  atomicAdd(&counts[d], 1);
}

// ---------------- KC: exclusive scan of counts -> row_start ----------------
__global__ __launch_bounds__(1024) void kc_scan(const int* __restrict__ counts,
                                                int* __restrict__ row_start) {
  __shared__ int wsum[16];
  __shared__ int s_carry;
  const int tid = threadIdx.x, lane = tid & 63, w = tid >> 6;
  if (tid == 0) s_carry = 0;
  __syncthreads();
  for (int base = 0; base < N_NODES; base += 1024) {
    const int i = base + tid;
    const int v = (i < N_NODES) ? counts[i] : 0;
    int inc = v;
#pragma unroll
    for (int off = 1; off < 64; off <<= 1) {
      int t = __shfl_up(inc, off);
      if (lane >= off) inc += t;
    }
    if (lane == 63) wsum[w] = inc;
    __syncthreads();
    if (w == 0 && lane < 16) {
      int s = wsum[lane];
      int sinc = s;
#pragma unroll
      for (int off = 1; off < 16; off <<= 1) {
        int t = __shfl_up(sinc, off);
        if (lane >= off) sinc += t;
      }
      wsum[lane] = sinc - s;  // exclusive wave offset
    }
    __syncthreads();
    const int excl = s_carry + wsum[w] + inc - v;
    if (i < N_NODES) row_start[i] = excl;
    __syncthreads();
    if (tid == 1023) s_carry += wsum[15] + inc;
    // next iteration's barriers order this write before any read
  }
}

// ---------------- KD: compute ev, scatter into dst-sorted order ----------------
__global__ __launch_bounds__(256) void kd_scatter(
    const int* __restrict__ ei,
    const float* __restrict__ a_src, const float* __restrict__ a_dst,
    const int* __restrict__ row_start, int* __restrict__ cursor,
    int* __restrict__ sorted_src, float* __restrict__ sorted_ev) {
  int e = blockIdx.x * 256 + threadIdx.x;
  int s = ei[e];
  int d = ei[E_EDGES + e];
  float a = a_src[s] + a_dst[d];
  a = a > 0.f ? a : NEG_SLOPE * a;
  float ev = __expf(a);
  int pos = row_start[d] + atomicAdd(&cursor[d], 1);
  sorted_src[pos] = s;
  sorted_ev[pos] = ev;
}

// ---------------- KE: per-dst gather-reduce (no atomics) ----------------
// one wave per dst node; lane owns 2 channels (float2)
__global__ __launch_bounds__(256) void ke_reduce(
    const int* __restrict__ row_start, const int* __restrict__ counts,
    const int* __restrict__ sorted_src, const float* __restrict__ sorted_ev,
    const float* __restrict__ x_proj, float* __restrict__ out) {
  const int w = blockIdx.x * 4 + (threadIdx.x >> 6);
  const int lane = threadIdx.x & 63;
  const int start = row_start[w];
  const int cnt = counts[w];
  float2 acc = make_float2(0.f, 0.f);
  float den = 0.f;
  int j = 0;
  // 2-deep manual pipeline to overlap the (src,ev) load with the gather
  if (cnt > 0) {
    int s0 = sorted_src[start];
    float ev0 = sorted_ev[start];
    for (j = 0; j + 1 < cnt; ++j) {
      const int s1 = sorted_src[start + j + 1];
      const float ev1 = sorted_ev[start + j + 1];
      const float2 v = ((const float2*)(x_proj + (size_t)s0 * HC))[lane];
      den += ev0;
      acc.x = fmaf(ev0, v.x, acc.x);
      acc.y = fmaf(ev0, v.y, acc.y);
      s0 = s1; ev0 = ev1;
    }
    const float2 v = ((const float2*)(x_proj + (size_t)s0 * HC))[lane];
    den += ev0;
    acc.x = fmaf(ev0, v.x, acc.x);
    acc.y = fmaf(ev0, v.y, acc.y);
  }
  const float inv = 1.f / (den + SM_EPS);
  float2* op = (float2*)(out + (size_t)w * HC) + lane;
  float2 o = *op;
  o.x += acc.x * inv;
  o.y += acc.y * inv;
  *op = o;
}

extern "C" void kernel_launch(void* const* d_in, const int* in_sizes, int n_in,
                              void* d_out, int out_size, void* d_ws, size_t ws_size,
                              hipStream_t stream) {
  const float* x         = (const float*)d_in[0];
  const int*   ei        = (const int*)d_in[1];
  const float* v_mapping = (const float*)d_in[2];
  const float* W_src     = (const float*)d_in[3];
  const float* att_src   = (const float*)d_in[4];
  const float* att_dst   = (const float*)d_in[5];
  const float* bias      = (const float*)d_in[6];
  float* out = (float*)d_out;

  char* ws = (char*)d_ws;
  float* x_proj     = (float*)ws;  ws += (size_t)N_NODES * HC * 4;   // 25.6 MB
  float* a_src      = (float*)ws;  ws += (size_t)N_NODES * 4;
  float* a_dst      = (float*)ws;  ws += (size_t)N_NODES * 4;
  float* wvec_src   = (float*)ws;  ws += 256 * 4;
  float* wvec_dst   = (float*)ws;  ws += 256 * 4;
  int*   counts     = (int*)ws;    ws += (size_t)N_NODES * 4;
  int*   cursor     = (int*)ws;    ws += (size_t)N_NODES * 4;
  int*   row_start  = (int*)ws;    ws += (size_t)N_NODES * 4;
  int*   sorted_src = (int*)ws;    ws += (size_t)E_EDGES * 4;        // 6.4 MB
  float* sorted_ev  = (float*)ws;  ws += (size_t)E_EDGES * 4;        // 6.4 MB

  k0_wvec<<<1, 256, 0, stream>>>(v_mapping, att_src, att_dst, wvec_src, wvec_dst);
  k1_node<<<N_NODES / 2, 256, 0, stream>>>(x, W_src, bias, wvec_src, wvec_dst,
                                           x_proj, out, a_src, a_dst);
  kz_zero<<<(N_NODES + 255) / 256, 256, 0, stream>>>(counts, cursor);
  kb_hist<<<E_EDGES / 256, 256, 0, stream>>>(ei, counts);
  kc_scan<<<1, 1024, 0, stream>>>(counts, row_start);
  kd_scatter<<<E_EDGES / 256, 256, 0, stream>>>(ei, a_src, a_dst, row_start,
                                                cursor, sorted_src, sorted_ev);
  ke_reduce<<<N_NODES / 4, 256, 0, stream>>>(row_start, counts, sorted_src,
                                             sorted_ev, x_proj, out);
}

// Round 3
// 381.660 us; speedup vs baseline: 4.1838x; 1.5234x over previous
//
#include <hip/hip_runtime.h>

#define N_NODES 50000
#define E_EDGES 1600000
#define HC 128
#define NEG_SLOPE 0.2f
#define SM_EPS 1e-16f

// ---------------- K0: wvec = v_mapping.T @ l2norm(att); zero gctr ----------------
__global__ __launch_bounds__(256) void k0_wvec(
    const float* __restrict__ v_mapping,  // [64,256]
    const float* __restrict__ att_src,    // [64]
    const float* __restrict__ att_dst,    // [64]
    float* __restrict__ wvec_src, float* __restrict__ wvec_dst,
    int* __restrict__ gctr) {
  int j = threadIdx.x;  // 0..255
  if (j == 0) *gctr = 0;
  float ns = 0.f, nd = 0.f;
  for (int f = 0; f < 64; ++f) {
    float a = att_src[f]; ns = fmaf(a, a, ns);
    float b = att_dst[f]; nd = fmaf(b, b, nd);
  }
  ns = fmaxf(sqrtf(ns), 1e-12f);
  nd = fmaxf(sqrtf(nd), 1e-12f);
  float ws_ = 0.f, wd_ = 0.f;
  for (int f = 0; f < 64; ++f) {
    float v = v_mapping[f * 256 + j];
    ws_ = fmaf(v, att_src[f], ws_);
    wd_ = fmaf(v, att_dst[f], wd_);
  }
  wvec_src[j] = ws_ / ns;
  wvec_dst[j] = wd_ / nd;
}

// ---------------- K1: node phase (register-tiled GEMM + dots) ----------------
// block: 64 rows x 128 cols; thread (ty=tid>>5, tx=tid&31): rows ty*8..+7, cols tx*4..+3
__global__ __launch_bounds__(256) void k1_node(
    const float* __restrict__ x,      // [N,256]
    const float* __restrict__ W,      // [256,128]
    const float* __restrict__ bias,   // [128]
    const float* __restrict__ wvec_src, const float* __restrict__ wvec_dst,
    float* __restrict__ x_proj,       // [N,128]
    float* __restrict__ out,          // [N,128]
    float* __restrict__ a_src, float* __restrict__ a_dst,
    int* __restrict__ counts, int* __restrict__ cursor) {
  __shared__ float xs[64][68];  // 64 rows x 64-k chunk, padded
  const int tid = threadIdx.x;
  const int rowbase = blockIdx.x * 64;
  const int ty = tid >> 5, tx = tid & 31;

  if (tid < 64) {
    int idx = rowbase + tid;
    if (idx < N_NODES) { counts[idx] = 0; cursor[idx] = 0; }
  }

  float acc[8][4];
#pragma unroll
  for (int i = 0; i < 8; ++i)
#pragma unroll
    for (int j = 0; j < 4; ++j) acc[i][j] = 0.f;

  float dot_part = 0.f;  // waves 0-1: a_src partial; waves 2-3: a_dst partial
  const int dl = tid & 127;           // 0..127 within wave-pair
  const int drow = dl >> 1;           // row 0..63
  const int dkh = (dl & 1) * 32;      // k-half offset
  const float* wv = (tid < 128) ? wvec_src : wvec_dst;

  const float4* W4 = (const float4*)W;
  const float4* x4 = (const float4*)x;

  for (int chunk = 0; chunk < 4; ++chunk) {
    const int cb16 = chunk * 16;  // chunk base in float4 units
    // stage x[rowbase..+63][chunk*64..+63] into xs
#pragma unroll
    for (int p = 0; p < 4; ++p) {
      const int row = (tid >> 4) + p * 16;
      const int k4 = tid & 15;
      float4 v = make_float4(0.f, 0.f, 0.f, 0.f);
      if (rowbase + row < N_NODES) v = x4[(size_t)(rowbase + row) * 64 + cb16 + k4];
      *(float4*)&xs[row][k4 * 4] = v;
    }
    __syncthreads();

    // GEMM inner loop over this chunk
#pragma unroll 4
    for (int k = 0; k < 64; ++k) {
      const float4 w4 = W4[(size_t)(chunk * 64 + k) * 32 + tx];
      float xv[8];
#pragma unroll
      for (int i = 0; i < 8; ++i) xv[i] = xs[ty * 8 + i][k];
#pragma unroll
      for (int i = 0; i < 8; ++i) {
        acc[i][0] = fmaf(xv[i], w4.x, acc[i][0]);
        acc[i][1] = fmaf(xv[i], w4.y, acc[i][1]);
        acc[i][2] = fmaf(xv[i], w4.z, acc[i][2]);
        acc[i][3] = fmaf(xv[i], w4.w, acc[i][3]);
      }
    }

    // attention-dot partials for this chunk
#pragma unroll 8
    for (int j = 0; j < 32; ++j)
      dot_part = fmaf(xs[drow][dkh + j], wv[chunk * 64 + dkh + j], dot_part);
    __syncthreads();
  }

  // finish dots: combine the two k-halves (adjacent lanes)
  {
    float tot = dot_part + __shfl_xor(dot_part, 1);
    const int row = rowbase + drow;
    if ((dl & 1) == 0 && row < N_NODES) {
      if (tid < 128) a_src[row] = tot;
      else a_dst[row] = tot;
    }
  }

  // store x_proj and out = x_proj + bias
  const float4 b4 = ((const float4*)bias)[tx];
#pragma unroll
  for (int i = 0; i < 8; ++i) {
    const int row = rowbase + ty * 8 + i;
    if (row < N_NODES) {
      float4 v = make_float4(acc[i][0], acc[i][1], acc[i][2], acc[i][3]);
      ((float4*)(x_proj + (size_t)row * HC))[tx] = v;
      float4 o = make_float4(v.x + b4.x, v.y + b4.y, v.z + b4.z, v.w + b4.w);
      ((float4*)(out + (size_t)row * HC))[tx] = o;
    }
  }
}

// ---------------- KB: dst histogram ----------------
__global__ __launch_bounds__(256) void kb_hist(const int* __restrict__ ei,
                                               int* __restrict__ counts) {
  int e = blockIdx.x * 256 + threadIdx.x;
  int d = ei[E_EDGES + e];
  atomicAdd(&counts[d], 1);
}

// ---------------- KR: range assign (block scan + one global atomic) ----------------
__global__ __launch_bounds__(256) void kr_range(const int* __restrict__ counts,
                                                int* __restrict__ row_start,
                                                int* __restrict__ gctr) {
  __shared__ int woff[4];
  __shared__ int s_base;
  const int i = blockIdx.x * 256 + threadIdx.x;
  const int lane = threadIdx.x & 63, w = threadIdx.x >> 6;
  const int c = (i < N_NODES) ? counts[i] : 0;
  int inc = c;
#pragma unroll
  for (int off = 1; off < 64; off <<= 1) {
    int t = __shfl_up(inc, off);
    if (lane >= off) inc += t;
  }
  if (lane == 63) woff[w] = inc;
  __syncthreads();
  if (threadIdx.x == 0) {
    int s = 0;
#pragma unroll
    for (int k = 0; k < 4; ++k) { int t = woff[k]; woff[k] = s; s += t; }
    s_base = atomicAdd(gctr, s);
  }
  __syncthreads();
  if (i < N_NODES) row_start[i] = s_base + woff[w] + inc - c;
}

// ---------------- KD: compute ev, scatter packed (src,ev) into buckets ----------------
__global__ __launch_bounds__(256) void kd_scatter(
    const int* __restrict__ ei,
    const float* __restrict__ a_src, const float* __restrict__ a_dst,
    const int* __restrict__ row_start, int* __restrict__ cursor,
    int2* __restrict__ sorted) {
  int e = blockIdx.x * 256 + threadIdx.x;
  int s = ei[e];
  int d = ei[E_EDGES + e];
  float a = a_src[s] + a_dst[d];
  a = a > 0.f ? a : NEG_SLOPE * a;
  float ev = __expf(a);
  int pos = row_start[d] + atomicAdd(&cursor[d], 1);
  sorted[pos] = make_int2(s, __float_as_int(ev));
}

// ---------------- KE: per-dst gather-reduce (no atomics) ----------------
__global__ __launch_bounds__(256) void ke_reduce(
    const int* __restrict__ row_start, const int* __restrict__ counts,
    const int2* __restrict__ sorted,
    const float* __restrict__ x_proj, float* __restrict__ out) {
  const int w = blockIdx.x * 4 + (threadIdx.x >> 6);
  const int lane = threadIdx.x & 63;
  const int start = row_start[w];
  const int cnt = counts[w];
  float2 acc = make_float2(0.f, 0.f);
  float den = 0.f;
  if (cnt > 0) {
    int2 sv = sorted[start];
    for (int j = 0; j + 1 < cnt; ++j) {
      const int2 nv = sorted[start + j + 1];
      const float ev = __int_as_float(sv.y);
      const float2 v = ((const float2*)(x_proj + (size_t)sv.x * HC))[lane];
      den += ev;
      acc.x = fmaf(ev, v.x, acc.x);
      acc.y = fmaf(ev, v.y, acc.y);
      sv = nv;
    }
    const float ev = __int_as_float(sv.y);
    const float2 v = ((const float2*)(x_proj + (size_t)sv.x * HC))[lane];
    den += ev;
    acc.x = fmaf(ev, v.x, acc.x);
    acc.y = fmaf(ev, v.y, acc.y);
  }
  const float inv = 1.f / (den + SM_EPS);
  float2* op = (float2*)(out + (size_t)w * HC) + lane;
  float2 o = *op;
  o.x += acc.x * inv;
  o.y += acc.y * inv;
  *op = o;
}

extern "C" void kernel_launch(void* const* d_in, const int* in_sizes, int n_in,
                              void* d_out, int out_size, void* d_ws, size_t ws_size,
                              hipStream_t stream) {
  const float* x         = (const float*)d_in[0];
  const int*   ei        = (const int*)d_in[1];
  const float* v_mapping = (const float*)d_in[2];
  const float* W_src     = (const float*)d_in[3];
  const float* att_src   = (const float*)d_in[4];
  const float* att_dst   = (const float*)d_in[5];
  const float* bias      = (const float*)d_in[6];
  float* out = (float*)d_out;

  char* ws = (char*)d_ws;
  float* x_proj     = (float*)ws;  ws += (size_t)N_NODES * HC * 4;   // 25.6 MB
  float* a_src      = (float*)ws;  ws += (size_t)N_NODES * 4;
  float* a_dst      = (float*)ws;  ws += (size_t)N_NODES * 4;
  float* wvec_src   = (float*)ws;  ws += 256 * 4;
  float* wvec_dst   = (float*)ws;  ws += 256 * 4;
  int*   counts     = (int*)ws;    ws += (size_t)N_NODES * 4;
  int*   cursor     = (int*)ws;    ws += (size_t)N_NODES * 4;
  int*   row_start  = (int*)ws;    ws += (size_t)N_NODES * 4;
  int*   gctr       = (int*)ws;    ws += 256;  // keep alignment
  int2*  sorted     = (int2*)ws;   ws += (size_t)E_EDGES * 8;        // 12.8 MB

  k0_wvec<<<1, 256, 0, stream>>>(v_mapping, att_src, att_dst, wvec_src, wvec_dst, gctr);
  k1_node<<<(N_NODES + 63) / 64, 256, 0, stream>>>(x, W_src, bias, wvec_src, wvec_dst,
                                                   x_proj, out, a_src, a_dst,
                                                   counts, cursor);
  kb_hist<<<E_EDGES / 256, 256, 0, stream>>>(ei, counts);
  kr_range<<<(N_NODES + 255) / 256, 256, 0, stream>>>(counts, row_start, gctr);
  kd_scatter<<<E_EDGES / 256, 256, 0, stream>>>(ei, a_src, a_dst, row_start,
                                                cursor, sorted);
  ke_reduce<<<N_NODES / 4, 256, 0, stream>>>(row_start, counts, sorted, x_proj, out);
}

// Round 4
// 336.265 us; speedup vs baseline: 4.7486x; 1.1350x over previous
//
#include <hip/hip_runtime.h>

#define N_NODES 50000
#define E_EDGES 1600000
#define HC 128
#define NEG_SLOPE 0.2f
#define SM_EPS 1e-16f

__device__ inline unsigned bf16pack(float a, float b) {
  unsigned ua = __float_as_uint(a), ub = __float_as_uint(b);
  ua = (ua + 0x7fffu + ((ua >> 16) & 1u)) >> 16;
  ub = (ub + 0x7fffu + ((ub >> 16) & 1u)) >> 16;
  return ua | (ub << 16);
}

// ---------------- K0: wvec = v_mapping.T @ l2norm(att); zero gctr ----------------
__global__ __launch_bounds__(256) void k0_wvec(
    const float* __restrict__ v_mapping,  // [64,256]
    const float* __restrict__ att_src,    // [64]
    const float* __restrict__ att_dst,    // [64]
    float* __restrict__ wvec_src, float* __restrict__ wvec_dst,
    int* __restrict__ gctr) {
  int j = threadIdx.x;  // 0..255
  if (j == 0) *gctr = 0;
  float ns = 0.f, nd = 0.f;
  for (int f = 0; f < 64; ++f) {
    float a = att_src[f]; ns = fmaf(a, a, ns);
    float b = att_dst[f]; nd = fmaf(b, b, nd);
  }
  ns = fmaxf(sqrtf(ns), 1e-12f);
  nd = fmaxf(sqrtf(nd), 1e-12f);
  float ws_ = 0.f, wd_ = 0.f;
  for (int f = 0; f < 64; ++f) {
    float v = v_mapping[f * 256 + j];
    ws_ = fmaf(v, att_src[f], ws_);
    wd_ = fmaf(v, att_dst[f], wd_);
  }
  wvec_src[j] = ws_ / ns;
  wvec_dst[j] = wd_ / nd;
}

// ---------------- K1: node phase (register-tiled GEMM + dots) ----------------
// block: 64 rows x 128 cols; thread (ty=tid>>5, tx=tid&31): rows ty*8..+7, cols tx*4..+3
__global__ __launch_bounds__(256) void k1_node(
    const float* __restrict__ x,      // [N,256]
    const float* __restrict__ W,      // [256,128]
    const float* __restrict__ wvec_src, const float* __restrict__ wvec_dst,
    float* __restrict__ x_proj,       // [N,128] f32
    unsigned* __restrict__ xpb,       // [N,64]  bf16x2 packed
    float* __restrict__ a_src, float* __restrict__ a_dst,
    int* __restrict__ counts, int* __restrict__ cursor) {
  __shared__ float xs[64][68];  // 64 rows x 64-k chunk, padded
  const int tid = threadIdx.x;
  const int rowbase = blockIdx.x * 64;
  const int ty = tid >> 5, tx = tid & 31;

  if (tid < 64) {
    int idx = rowbase + tid;
    if (idx < N_NODES) { counts[idx] = 0; cursor[idx] = 0; }
  }

  float acc[8][4];
#pragma unroll
  for (int i = 0; i < 8; ++i)
#pragma unroll
    for (int j = 0; j < 4; ++j) acc[i][j] = 0.f;

  float dot_part = 0.f;  // waves 0-1: a_src partial; waves 2-3: a_dst partial
  const int dl = tid & 127;           // 0..127 within wave-pair
  const int drow = dl >> 1;           // row 0..63
  const int dkh = (dl & 1) * 32;      // k-half offset
  const float* wv = (tid < 128) ? wvec_src : wvec_dst;

  const float4* W4 = (const float4*)W;
  const float4* x4 = (const float4*)x;

  for (int chunk = 0; chunk < 4; ++chunk) {
    const int cb16 = chunk * 16;  // chunk base in float4 units
#pragma unroll
    for (int p = 0; p < 4; ++p) {
      const int row = (tid >> 4) + p * 16;
      const int k4 = tid & 15;
      float4 v = make_float4(0.f, 0.f, 0.f, 0.f);
      if (rowbase + row < N_NODES) v = x4[(size_t)(rowbase + row) * 64 + cb16 + k4];
      *(float4*)&xs[row][k4 * 4] = v;
    }
    __syncthreads();

#pragma unroll 4
    for (int k = 0; k < 64; ++k) {
      const float4 w4 = W4[(size_t)(chunk * 64 + k) * 32 + tx];
      float xv[8];
#pragma unroll
      for (int i = 0; i < 8; ++i) xv[i] = xs[ty * 8 + i][k];
#pragma unroll
      for (int i = 0; i < 8; ++i) {
        acc[i][0] = fmaf(xv[i], w4.x, acc[i][0]);
        acc[i][1] = fmaf(xv[i], w4.y, acc[i][1]);
        acc[i][2] = fmaf(xv[i], w4.z, acc[i][2]);
        acc[i][3] = fmaf(xv[i], w4.w, acc[i][3]);
      }
    }

#pragma unroll 8
    for (int j = 0; j < 32; ++j)
      dot_part = fmaf(xs[drow][dkh + j], wv[chunk * 64 + dkh + j], dot_part);
    __syncthreads();
  }

  {
    float tot = dot_part + __shfl_xor(dot_part, 1);
    const int row = rowbase + drow;
    if ((dl & 1) == 0 && row < N_NODES) {
      if (tid < 128) a_src[row] = tot;
      else a_dst[row] = tot;
    }
  }

#pragma unroll
  for (int i = 0; i < 8; ++i) {
    const int row = rowbase + ty * 8 + i;
    if (row < N_NODES) {
      float4 v = make_float4(acc[i][0], acc[i][1], acc[i][2], acc[i][3]);
      ((float4*)(x_proj + (size_t)row * HC))[tx] = v;
      uint2 p;
      p.x = bf16pack(v.x, v.y);
      p.y = bf16pack(v.z, v.w);
      ((uint2*)(xpb + (size_t)row * 64))[tx] = p;
    }
  }
}

// ---------------- KB: dst histogram ----------------
__global__ __launch_bounds__(256) void kb_hist(const int* __restrict__ ei,
                                               int* __restrict__ counts) {
  int e = blockIdx.x * 256 + threadIdx.x;
  int d = ei[E_EDGES + e];
  atomicAdd(&counts[d], 1);
}

// ---------------- KR: range assign (block scan + one global atomic) ----------------
__global__ __launch_bounds__(256) void kr_range(const int* __restrict__ counts,
                                                int* __restrict__ row_start,
                                                int* __restrict__ gctr) {
  __shared__ int woff[4];
  __shared__ int s_base;
  const int i = blockIdx.x * 256 + threadIdx.x;
  const int lane = threadIdx.x & 63, w = threadIdx.x >> 6;
  const int c = (i < N_NODES) ? counts[i] : 0;
  int inc = c;
#pragma unroll
  for (int off = 1; off < 64; off <<= 1) {
    int t = __shfl_up(inc, off);
    if (lane >= off) inc += t;
  }
  if (lane == 63) woff[w] = inc;
  __syncthreads();
  if (threadIdx.x == 0) {
    int s = 0;
#pragma unroll
    for (int k = 0; k < 4; ++k) { int t = woff[k]; woff[k] = s; s += t; }
    s_base = atomicAdd(gctr, s);
  }
  __syncthreads();
  if (i < N_NODES) row_start[i] = s_base + woff[w] + inc - c;
}

// ---------------- KD: permutation scatter (dst-bucketed src list) ----------------
__global__ __launch_bounds__(256) void kd_scatter(
    const int* __restrict__ ei,
    const int* __restrict__ row_start, int* __restrict__ cursor,
    int* __restrict__ sorted_src) {
  int e = blockIdx.x * 256 + threadIdx.x;
  int s = ei[e];
  int d = ei[E_EDGES + e];
  int pos = row_start[d] + atomicAdd(&cursor[d], 1);
  sorted_src[pos] = s;
}

// ---------------- KE: per-dst gather-reduce (bf16 gather, writes out) ----------------
__global__ __launch_bounds__(256) void ke_reduce(
    const int* __restrict__ row_start, const int* __restrict__ counts,
    const int* __restrict__ sorted_src,
    const float* __restrict__ a_src, const float* __restrict__ a_dst,
    const unsigned* __restrict__ xpb,   // [N,64] bf16x2
    const float* __restrict__ x_proj,   // [N,128] f32
    const float* __restrict__ bias,     // [128]
    float* __restrict__ out) {
  const int w = blockIdx.x * 4 + (threadIdx.x >> 6);
  const int lane = threadIdx.x & 63;
  const int start = row_start[w];
  const int cnt = counts[w];
  const float adw = a_dst[w];
  float2 acc = make_float2(0.f, 0.f);
  float den = 0.f;

  int j = 0;
  if (cnt > 0) {
    int sA = sorted_src[start];
    for (; j + 2 <= cnt; j += 2) {
      const int sB = sorted_src[start + j + 1];
      const int sC = (j + 2 < cnt) ? sorted_src[start + j + 2] : 0;
      const unsigned uA = xpb[(size_t)sA * 64 + lane];
      const unsigned uB = xpb[(size_t)sB * 64 + lane];
      float aA = a_src[sA] + adw; aA = aA > 0.f ? aA : NEG_SLOPE * aA;
      float aB = a_src[sB] + adw; aB = aB > 0.f ? aB : NEG_SLOPE * aB;
      const float evA = __expf(aA);
      const float evB = __expf(aB);
      den += evA + evB;
      acc.x = fmaf(evA, __uint_as_float(uA << 16), acc.x);
      acc.y = fmaf(evA, __uint_as_float(uA & 0xffff0000u), acc.y);
      acc.x = fmaf(evB, __uint_as_float(uB << 16), acc.x);
      acc.y = fmaf(evB, __uint_as_float(uB & 0xffff0000u), acc.y);
      sA = sC;
    }
    if (j < cnt) {
      const unsigned uA = xpb[(size_t)sA * 64 + lane];
      float aA = a_src[sA] + adw; aA = aA > 0.f ? aA : NEG_SLOPE * aA;
      const float evA = __expf(aA);
      den += evA;
      acc.x = fmaf(evA, __uint_as_float(uA << 16), acc.x);
      acc.y = fmaf(evA, __uint_as_float(uA & 0xffff0000u), acc.y);
    }
  }

  const float inv = 1.f / (den + SM_EPS);
  const float2 xp = ((const float2*)(x_proj + (size_t)w * HC))[lane];
  const float2 b2 = ((const float2*)bias)[lane];
  float2 o;
  o.x = xp.x + b2.x + acc.x * inv;
  o.y = xp.y + b2.y + acc.y * inv;
  ((float2*)(out + (size_t)w * HC))[lane] = o;
}

extern "C" void kernel_launch(void* const* d_in, const int* in_sizes, int n_in,
                              void* d_out, int out_size, void* d_ws, size_t ws_size,
                              hipStream_t stream) {
  const float* x         = (const float*)d_in[0];
  const int*   ei        = (const int*)d_in[1];
  const float* v_mapping = (const float*)d_in[2];
  const float* W_src     = (const float*)d_in[3];
  const float* att_src   = (const float*)d_in[4];
  const float* att_dst   = (const float*)d_in[5];
  const float* bias      = (const float*)d_in[6];
  float* out = (float*)d_out;

  char* ws = (char*)d_ws;
  float*    x_proj     = (float*)ws;     ws += (size_t)N_NODES * HC * 4;  // 25.6 MB
  unsigned* xpb        = (unsigned*)ws;  ws += (size_t)N_NODES * 64 * 4;  // 12.8 MB
  float*    a_src      = (float*)ws;     ws += (size_t)N_NODES * 4;
  float*    a_dst      = (float*)ws;     ws += (size_t)N_NODES * 4;
  float*    wvec_src   = (float*)ws;     ws += 256 * 4;
  float*    wvec_dst   = (float*)ws;     ws += 256 * 4;
  int*      counts     = (int*)ws;       ws += (size_t)N_NODES * 4;
  int*      cursor     = (int*)ws;       ws += (size_t)N_NODES * 4;
  int*      row_start  = (int*)ws;       ws += (size_t)N_NODES * 4;
  int*      gctr       = (int*)ws;       ws += 256;
  int*      sorted_src = (int*)ws;       ws += (size_t)E_EDGES * 4;       // 6.4 MB

  k0_wvec<<<1, 256, 0, stream>>>(v_mapping, att_src, att_dst, wvec_src, wvec_dst, gctr);
  k1_node<<<(N_NODES + 63) / 64, 256, 0, stream>>>(x, W_src, wvec_src, wvec_dst,
                                                   x_proj, xpb, a_src, a_dst,
                                                   counts, cursor);
  kb_hist<<<E_EDGES / 256, 256, 0, stream>>>(ei, counts);
  kr_range<<<(N_NODES + 255) / 256, 256, 0, stream>>>(counts, row_start, gctr);
  kd_scatter<<<E_EDGES / 256, 256, 0, stream>>>(ei, row_start, cursor, sorted_src);
  ke_reduce<<<N_NODES / 4, 256, 0, stream>>>(row_start, counts, sorted_src,
                                             a_src, a_dst, xpb, x_proj, bias, out);
}

// Round 5
// 260.497 us; speedup vs baseline: 6.1297x; 1.2909x over previous
//
#include <hip/hip_runtime.h>

#define N_NODES 50000
#define E_EDGES 1600000
#define HC 128
#define NEG_SLOPE 0.2f
#define SM_EPS 1e-16f

__device__ inline unsigned bf16pack(float a, float b) {
  unsigned ua = __float_as_uint(a), ub = __float_as_uint(b);
  ua = (ua + 0x7fffu + ((ua >> 16) & 1u)) >> 16;
  ub = (ub + 0x7fffu + ((ub >> 16) & 1u)) >> 16;
  return ua | (ub << 16);
}

// ---------------- K0: wvec = v_mapping.T @ l2norm(att); zero gctr ----------------
__global__ __launch_bounds__(256) void k0_wvec(
    const float* __restrict__ v_mapping,  // [64,256]
    const float* __restrict__ att_src,    // [64]
    const float* __restrict__ att_dst,    // [64]
    float* __restrict__ wvec_src, float* __restrict__ wvec_dst,
    int* __restrict__ gctr) {
  int j = threadIdx.x;  // 0..255
  if (j == 0) *gctr = 0;
  float ns = 0.f, nd = 0.f;
  for (int f = 0; f < 64; ++f) {
    float a = att_src[f]; ns = fmaf(a, a, ns);
    float b = att_dst[f]; nd = fmaf(b, b, nd);
  }
  ns = fmaxf(sqrtf(ns), 1e-12f);
  nd = fmaxf(sqrtf(nd), 1e-12f);
  float ws_ = 0.f, wd_ = 0.f;
  for (int f = 0; f < 64; ++f) {
    float v = v_mapping[f * 256 + j];
    ws_ = fmaf(v, att_src[f], ws_);
    wd_ = fmaf(v, att_dst[f], wd_);
  }
  wvec_src[j] = ws_ / ns;
  wvec_dst[j] = wd_ / nd;
}

// ---------------- K1: node phase (register-tiled GEMM + dots) ----------------
// block: 64 rows x 128 cols; thread (ty=tid>>5, tx=tid&31): rows ty*8..+7, cols tx*4..+3
__global__ __launch_bounds__(256) void k1_node(
    const float* __restrict__ x,      // [N,256]
    const float* __restrict__ W,      // [256,128]
    const float* __restrict__ wvec_src, const float* __restrict__ wvec_dst,
    float* __restrict__ x_proj,       // [N,128] f32
    unsigned* __restrict__ xpb,       // [N,64]  bf16x2 packed
    float* __restrict__ a_src, float* __restrict__ a_dst,
    int* __restrict__ counts) {
  __shared__ float xs[64][68];  // 64 rows x 64-k chunk, padded
  const int tid = threadIdx.x;
  const int rowbase = blockIdx.x * 64;
  const int ty = tid >> 5, tx = tid & 31;

  if (tid < 64) {
    int idx = rowbase + tid;
    if (idx < N_NODES) counts[idx] = 0;
  }

  float acc[8][4];
#pragma unroll
  for (int i = 0; i < 8; ++i)
#pragma unroll
    for (int j = 0; j < 4; ++j) acc[i][j] = 0.f;

  float dot_part = 0.f;  // waves 0-1: a_src partial; waves 2-3: a_dst partial
  const int dl = tid & 127;           // 0..127 within wave-pair
  const int drow = dl >> 1;           // row 0..63
  const int dkh = (dl & 1) * 32;      // k-half offset
  const float* wv = (tid < 128) ? wvec_src : wvec_dst;

  const float4* W4 = (const float4*)W;
  const float4* x4 = (const float4*)x;

  for (int chunk = 0; chunk < 4; ++chunk) {
    const int cb16 = chunk * 16;  // chunk base in float4 units
#pragma unroll
    for (int p = 0; p < 4; ++p) {
      const int row = (tid >> 4) + p * 16;
      const int k4 = tid & 15;
      float4 v = make_float4(0.f, 0.f, 0.f, 0.f);
      if (rowbase + row < N_NODES) v = x4[(size_t)(rowbase + row) * 64 + cb16 + k4];
      *(float4*)&xs[row][k4 * 4] = v;
    }
    __syncthreads();

#pragma unroll 4
    for (int k = 0; k < 64; ++k) {
      const float4 w4 = W4[(size_t)(chunk * 64 + k) * 32 + tx];
      float xv[8];
#pragma unroll
      for (int i = 0; i < 8; ++i) xv[i] = xs[ty * 8 + i][k];
#pragma unroll
      for (int i = 0; i < 8; ++i) {
        acc[i][0] = fmaf(xv[i], w4.x, acc[i][0]);
        acc[i][1] = fmaf(xv[i], w4.y, acc[i][1]);
        acc[i][2] = fmaf(xv[i], w4.z, acc[i][2]);
        acc[i][3] = fmaf(xv[i], w4.w, acc[i][3]);
      }
    }

#pragma unroll 8
    for (int j = 0; j < 32; ++j)
      dot_part = fmaf(xs[drow][dkh + j], wv[chunk * 64 + dkh + j], dot_part);
    __syncthreads();
  }

  {
    float tot = dot_part + __shfl_xor(dot_part, 1);
    const int row = rowbase + drow;
    if ((dl & 1) == 0 && row < N_NODES) {
      if (tid < 128) a_src[row] = tot;
      else a_dst[row] = tot;
    }
  }

#pragma unroll
  for (int i = 0; i < 8; ++i) {
    const int row = rowbase + ty * 8 + i;
    if (row < N_NODES) {
      float4 v = make_float4(acc[i][0], acc[i][1], acc[i][2], acc[i][3]);
      ((float4*)(x_proj + (size_t)row * HC))[tx] = v;
      uint2 p;
      p.x = bf16pack(v.x, v.y);
      p.y = bf16pack(v.z, v.w);
      ((uint2*)(xpb + (size_t)row * 64))[tx] = p;
    }
  }
}

// ---------------- KB: dst histogram + per-edge rank ----------------
__global__ __launch_bounds__(256) void kb_hist(const int* __restrict__ ei,
                                               int* __restrict__ counts,
                                               int* __restrict__ rank) {
  int e = blockIdx.x * 256 + threadIdx.x;
  int d = ei[E_EDGES + e];
  rank[e] = atomicAdd(&counts[d], 1);  // coalesced store; no dependent consumer here
}

// ---------------- KR: range assign (block scan + one global atomic) ----------------
__global__ __launch_bounds__(256) void kr_range(const int* __restrict__ counts,
                                                int* __restrict__ row_start,
                                                int* __restrict__ gctr) {
  __shared__ int woff[4];
  __shared__ int s_base;
  const int i = blockIdx.x * 256 + threadIdx.x;
  const int lane = threadIdx.x & 63, w = threadIdx.x >> 6;
  const int c = (i < N_NODES) ? counts[i] : 0;
  int inc = c;
#pragma unroll
  for (int off = 1; off < 64; off <<= 1) {
    int t = __shfl_up(inc, off);
    if (lane >= off) inc += t;
  }
  if (lane == 63) woff[w] = inc;
  __syncthreads();
  if (threadIdx.x == 0) {
    int s = 0;
#pragma unroll
    for (int k = 0; k < 4; ++k) { int t = woff[k]; woff[k] = s; s += t; }
    s_base = atomicAdd(gctr, s);
  }
  __syncthreads();
  if (i < N_NODES) row_start[i] = s_base + woff[w] + inc - c;
}

// ---------------- KD: permutation scatter, atomic-free ----------------
__global__ __launch_bounds__(256) void kd_scatter(
    const int* __restrict__ ei,
    const int* __restrict__ row_start, const int* __restrict__ rank,
    int* __restrict__ sorted_src) {
  int e = blockIdx.x * 256 + threadIdx.x;
  int s = ei[e];
  int d = ei[E_EDGES + e];
  sorted_src[row_start[d] + rank[e]] = s;
}

// ---------------- KE: per-dst gather-reduce (bf16 gather, writes out) ----------------
__global__ __launch_bounds__(256) void ke_reduce(
    const int* __restrict__ row_start, const int* __restrict__ counts,
    const int* __restrict__ sorted_src,
    const float* __restrict__ a_src, const float* __restrict__ a_dst,
    const unsigned* __restrict__ xpb,   // [N,64] bf16x2
    const float* __restrict__ x_proj,   // [N,128] f32
    const float* __restrict__ bias,     // [128]
    float* __restrict__ out) {
  const int w = blockIdx.x * 4 + (threadIdx.x >> 6);
  const int lane = threadIdx.x & 63;
  const int start = row_start[w];
  const int cnt = counts[w];
  const float adw = a_dst[w];
  float2 acc = make_float2(0.f, 0.f);
  float den = 0.f;

  int j = 0;
  if (cnt > 0) {
    int sA = sorted_src[start];
    for (; j + 2 <= cnt; j += 2) {
      const int sB = sorted_src[start + j + 1];
      const int sC = (j + 2 < cnt) ? sorted_src[start + j + 2] : 0;
      const unsigned uA = xpb[(size_t)sA * 64 + lane];
      const unsigned uB = xpb[(size_t)sB * 64 + lane];
      float aA = a_src[sA] + adw; aA = aA > 0.f ? aA : NEG_SLOPE * aA;
      float aB = a_src[sB] + adw; aB = aB > 0.f ? aB : NEG_SLOPE * aB;
      const float evA = __expf(aA);
      const float evB = __expf(aB);
      den += evA + evB;
      acc.x = fmaf(evA, __uint_as_float(uA << 16), acc.x);
      acc.y = fmaf(evA, __uint_as_float(uA & 0xffff0000u), acc.y);
      acc.x = fmaf(evB, __uint_as_float(uB << 16), acc.x);
      acc.y = fmaf(evB, __uint_as_float(uB & 0xffff0000u), acc.y);
      sA = sC;
    }
    if (j < cnt) {
      const unsigned uA = xpb[(size_t)sA * 64 + lane];
      float aA = a_src[sA] + adw; aA = aA > 0.f ? aA : NEG_SLOPE * aA;
      const float evA = __expf(aA);
      den += evA;
      acc.x = fmaf(evA, __uint_as_float(uA << 16), acc.x);
      acc.y = fmaf(evA, __uint_as_float(uA & 0xffff0000u), acc.y);
    }
  }

  const float inv = 1.f / (den + SM_EPS);
  const float2 xp = ((const float2*)(x_proj + (size_t)w * HC))[lane];
  const float2 b2 = ((const float2*)bias)[lane];
  float2 o;
  o.x = xp.x + b2.x + acc.x * inv;
  o.y = xp.y + b2.y + acc.y * inv;
  ((float2*)(out + (size_t)w * HC))[lane] = o;
}

extern "C" void kernel_launch(void* const* d_in, const int* in_sizes, int n_in,
                              void* d_out, int out_size, void* d_ws, size_t ws_size,
                              hipStream_t stream) {
  const float* x         = (const float*)d_in[0];
  const int*   ei        = (const int*)d_in[1];
  const float* v_mapping = (const float*)d_in[2];
  const float* W_src     = (const float*)d_in[3];
  const float* att_src   = (const float*)d_in[4];
  const float* att_dst   = (const float*)d_in[5];
  const float* bias      = (const float*)d_in[6];
  float* out = (float*)d_out;

  char* ws = (char*)d_ws;
  float*    x_proj     = (float*)ws;     ws += (size_t)N_NODES * HC * 4;  // 25.6 MB
  unsigned* xpb        = (unsigned*)ws;  ws += (size_t)N_NODES * 64 * 4;  // 12.8 MB
  float*    a_src      = (float*)ws;     ws += (size_t)N_NODES * 4;
  float*    a_dst      = (float*)ws;     ws += (size_t)N_NODES * 4;
  float*    wvec_src   = (float*)ws;     ws += 256 * 4;
  float*    wvec_dst   = (float*)ws;     ws += 256 * 4;
  int*      counts     = (int*)ws;       ws += (size_t)N_NODES * 4;
  int*      row_start  = (int*)ws;       ws += (size_t)N_NODES * 4;
  int*      gctr       = (int*)ws;       ws += 256;
  int*      rank       = (int*)ws;       ws += (size_t)E_EDGES * 4;       // 6.4 MB
  int*      sorted_src = (int*)ws;       ws += (size_t)E_EDGES * 4;       // 6.4 MB

  k0_wvec<<<1, 256, 0, stream>>>(v_mapping, att_src, att_dst, wvec_src, wvec_dst, gctr);
  k1_node<<<(N_NODES + 63) / 64, 256, 0, stream>>>(x, W_src, wvec_src, wvec_dst,
                                                   x_proj, xpb, a_src, a_dst, counts);
  kb_hist<<<E_EDGES / 256, 256, 0, stream>>>(ei, counts, rank);
  kr_range<<<(N_NODES + 255) / 256, 256, 0, stream>>>(counts, row_start, gctr);
  kd_scatter<<<E_EDGES / 256, 256, 0, stream>>>(ei, row_start, rank, sorted_src);
  ke_reduce<<<N_NODES / 4, 256, 0, stream>>>(row_start, counts, sorted_src,
                                             a_src, a_dst, xpb, x_proj, bias, out);
}

// Round 6
// 239.927 us; speedup vs baseline: 6.6553x; 1.0857x over previous
//
#include <hip/hip_runtime.h>

#define N_NODES 50000
#define E_EDGES 1600000
#define HC 128
#define NEG_SLOPE 0.2f
#define SM_EPS 1e-16f

__device__ inline unsigned bf16pack(float a, float b) {
  unsigned ua = __float_as_uint(a), ub = __float_as_uint(b);
  ua = (ua + 0x7fffu + ((ua >> 16) & 1u)) >> 16;
  ub = (ub + 0x7fffu + ((ub >> 16) & 1u)) >> 16;
  return ua | (ub << 16);
}

// ---------------- K0: wvec = v_mapping.T @ l2norm(att); zero gctr ----------------
__global__ __launch_bounds__(256) void k0_wvec(
    const float* __restrict__ v_mapping,  // [64,256]
    const float* __restrict__ att_src,    // [64]
    const float* __restrict__ att_dst,    // [64]
    float* __restrict__ wvec_src, float* __restrict__ wvec_dst,
    int* __restrict__ gctr) {
  int j = threadIdx.x;  // 0..255
  if (j == 0) *gctr = 0;
  float ns = 0.f, nd = 0.f;
  for (int f = 0; f < 64; ++f) {
    float a = att_src[f]; ns = fmaf(a, a, ns);
    float b = att_dst[f]; nd = fmaf(b, b, nd);
  }
  ns = fmaxf(sqrtf(ns), 1e-12f);
  nd = fmaxf(sqrtf(nd), 1e-12f);
  float ws_ = 0.f, wd_ = 0.f;
  for (int f = 0; f < 64; ++f) {
    float v = v_mapping[f * 256 + j];
    ws_ = fmaf(v, att_src[f], ws_);
    wd_ = fmaf(v, att_dst[f], wd_);
  }
  wvec_src[j] = ws_ / ns;
  wvec_dst[j] = wd_ / nd;
}

// ---------------- K1: node phase (register-tiled GEMM + dots) ----------------
// block: 64 rows x 128 cols; thread (ty=tid>>5, tx=tid&31): rows ty*8..+7, cols tx*4..+3
__global__ __launch_bounds__(256) void k1_node(
    const float* __restrict__ x,      // [N,256]
    const float* __restrict__ W,      // [256,128]
    const float* __restrict__ wvec_src, const float* __restrict__ wvec_dst,
    float* __restrict__ x_proj,       // [N,128] f32
    unsigned* __restrict__ xpb,       // [N,64]  bf16x2 packed
    float* __restrict__ a_src, float* __restrict__ a_dst,
    int* __restrict__ counts) {
  __shared__ float xs[64][68];  // 64 rows x 64-k chunk, padded
  const int tid = threadIdx.x;
  const int rowbase = blockIdx.x * 64;
  const int ty = tid >> 5, tx = tid & 31;

  if (tid < 64) {
    int idx = rowbase + tid;
    if (idx < N_NODES) counts[idx] = 0;
  }

  float acc[8][4];
#pragma unroll
  for (int i = 0; i < 8; ++i)
#pragma unroll
    for (int j = 0; j < 4; ++j) acc[i][j] = 0.f;

  float dot_part = 0.f;  // waves 0-1: a_src partial; waves 2-3: a_dst partial
  const int dl = tid & 127;           // 0..127 within wave-pair
  const int drow = dl >> 1;           // row 0..63
  const int dkh = (dl & 1) * 32;      // k-half offset
  const float* wv = (tid < 128) ? wvec_src : wvec_dst;

  const float4* W4 = (const float4*)W;
  const float4* x4 = (const float4*)x;

  for (int chunk = 0; chunk < 4; ++chunk) {
    const int cb16 = chunk * 16;  // chunk base in float4 units
#pragma unroll
    for (int p = 0; p < 4; ++p) {
      const int row = (tid >> 4) + p * 16;
      const int k4 = tid & 15;
      float4 v = make_float4(0.f, 0.f, 0.f, 0.f);
      if (rowbase + row < N_NODES) v = x4[(size_t)(rowbase + row) * 64 + cb16 + k4];
      *(float4*)&xs[row][k4 * 4] = v;
    }
    __syncthreads();

#pragma unroll 4
    for (int k = 0; k < 64; ++k) {
      const float4 w4 = W4[(size_t)(chunk * 64 + k) * 32 + tx];
      float xv[8];
#pragma unroll
      for (int i = 0; i < 8; ++i) xv[i] = xs[ty * 8 + i][k];
#pragma unroll
      for (int i = 0; i < 8; ++i) {
        acc[i][0] = fmaf(xv[i], w4.x, acc[i][0]);
        acc[i][1] = fmaf(xv[i], w4.y, acc[i][1]);
        acc[i][2] = fmaf(xv[i], w4.z, acc[i][2]);
        acc[i][3] = fmaf(xv[i], w4.w, acc[i][3]);
      }
    }

#pragma unroll 8
    for (int j = 0; j < 32; ++j)
      dot_part = fmaf(xs[drow][dkh + j], wv[chunk * 64 + dkh + j], dot_part);
    __syncthreads();
  }

  {
    float tot = dot_part + __shfl_xor(dot_part, 1);
    const int row = rowbase + drow;
    if ((dl & 1) == 0 && row < N_NODES) {
      if (tid < 128) a_src[row] = tot;
      else a_dst[row] = tot;
    }
  }

#pragma unroll
  for (int i = 0; i < 8; ++i) {
    const int row = rowbase + ty * 8 + i;
    if (row < N_NODES) {
      float4 v = make_float4(acc[i][0], acc[i][1], acc[i][2], acc[i][3]);
      ((float4*)(x_proj + (size_t)row * HC))[tx] = v;
      uint2 p;
      p.x = bf16pack(v.x, v.y);
      p.y = bf16pack(v.z, v.w);
      ((uint2*)(xpb + (size_t)row * 64))[tx] = p;
    }
  }
}

// ---------------- KB: dst histogram + per-edge rank ----------------
__global__ __launch_bounds__(256) void kb_hist(const int* __restrict__ ei,
                                               int* __restrict__ counts,
                                               int* __restrict__ rank) {
  int e = blockIdx.x * 256 + threadIdx.x;
  int d = ei[E_EDGES + e];
  rank[e] = atomicAdd(&counts[d], 1);  // coalesced store; no dependent consumer here
}

// ---------------- KR: range assign (block scan + one global atomic) ----------------
__global__ __launch_bounds__(256) void kr_range(const int* __restrict__ counts,
                                                int* __restrict__ row_start,
                                                int* __restrict__ gctr) {
  __shared__ int woff[4];
  __shared__ int s_base;
  const int i = blockIdx.x * 256 + threadIdx.x;
  const int lane = threadIdx.x & 63, w = threadIdx.x >> 6;
  const int c = (i < N_NODES) ? counts[i] : 0;
  int inc = c;
#pragma unroll
  for (int off = 1; off < 64; off <<= 1) {
    int t = __shfl_up(inc, off);
    if (lane >= off) inc += t;
  }
  if (lane == 63) woff[w] = inc;
  __syncthreads();
  if (threadIdx.x == 0) {
    int s = 0;
#pragma unroll
    for (int k = 0; k < 4; ++k) { int t = woff[k]; woff[k] = s; s += t; }
    s_base = atomicAdd(gctr, s);
  }
  __syncthreads();
  if (i < N_NODES) row_start[i] = s_base + woff[w] + inc - c;
}

// ---------------- KD: compute ev, permutation scatter of (src, ev), atomic-free ----
__global__ __launch_bounds__(256) void kd_scatter(
    const int* __restrict__ ei,
    const float* __restrict__ a_src, const float* __restrict__ a_dst,
    const int* __restrict__ row_start, const int* __restrict__ rank,
    int2* __restrict__ sorted) {
  int e = blockIdx.x * 256 + threadIdx.x;
  int s = ei[e];
  int d = ei[E_EDGES + e];
  float a = a_src[s] + a_dst[d];
  a = a > 0.f ? a : NEG_SLOPE * a;
  const float ev = __expf(a);
  sorted[row_start[d] + rank[e]] = make_int2(s, __float_as_int(ev));
}

// ---------------- KE: per-dst gather-reduce, 16 lanes/dst, uint4 gather ----------
__global__ __launch_bounds__(256) void ke_reduce(
    const int* __restrict__ row_start, const int* __restrict__ counts,
    const int2* __restrict__ sorted,
    const unsigned* __restrict__ xpb,   // [N,64] bf16x2
    const float* __restrict__ x_proj,   // [N,128] f32
    const float* __restrict__ bias,     // [128]
    float* __restrict__ out) {
  const int tid = threadIdx.x;
  const int w = tid >> 6;
  const int lane = tid & 63;
  const int g = lane >> 4;     // group 0..3 (one dst per group)
  const int gl = lane & 15;    // lane within group: owns channels 8*gl..8*gl+7
  const int dst = blockIdx.x * 16 + w * 4 + g;
  const int start = row_start[dst];
  const int cnt = counts[dst];

  float acc[8];
#pragma unroll
  for (int i = 0; i < 8; ++i) acc[i] = 0.f;
  float den = 0.f;

  const int2* sp = sorted + start;
  const uint4* xp4 = (const uint4*)xpb;

  if (cnt > 0) {
    int2 se = sp[0];
    for (int j = 0; j + 1 < cnt; ++j) {
      const int2 sn = sp[j + 1];
      const uint4 u = xp4[(size_t)se.x * 16 + gl];
      const float ev = __int_as_float(se.y);
      den += ev;
      acc[0] = fmaf(ev, __uint_as_float(u.x << 16), acc[0]);
      acc[1] = fmaf(ev, __uint_as_float(u.x & 0xffff0000u), acc[1]);
      acc[2] = fmaf(ev, __uint_as_float(u.y << 16), acc[2]);
      acc[3] = fmaf(ev, __uint_as_float(u.y & 0xffff0000u), acc[3]);
      acc[4] = fmaf(ev, __uint_as_float(u.z << 16), acc[4]);
      acc[5] = fmaf(ev, __uint_as_float(u.z & 0xffff0000u), acc[5]);
      acc[6] = fmaf(ev, __uint_as_float(u.w << 16), acc[6]);
      acc[7] = fmaf(ev, __uint_as_float(u.w & 0xffff0000u), acc[7]);
      se = sn;
    }
    {
      const uint4 u = xp4[(size_t)se.x * 16 + gl];
      const float ev = __int_as_float(se.y);
      den += ev;
      acc[0] = fmaf(ev, __uint_as_float(u.x << 16), acc[0]);
      acc[1] = fmaf(ev, __uint_as_float(u.x & 0xffff0000u), acc[1]);
      acc[2] = fmaf(ev, __uint_as_float(u.y << 16), acc[2]);
      acc[3] = fmaf(ev, __uint_as_float(u.y & 0xffff0000u), acc[3]);
      acc[4] = fmaf(ev, __uint_as_float(u.z << 16), acc[4]);
      acc[5] = fmaf(ev, __uint_as_float(u.z & 0xffff0000u), acc[5]);
      acc[6] = fmaf(ev, __uint_as_float(u.w << 16), acc[6]);
      acc[7] = fmaf(ev, __uint_as_float(u.w & 0xffff0000u), acc[7]);
    }
  }

  const float inv = 1.f / (den + SM_EPS);
  const float4* xr = (const float4*)(x_proj + (size_t)dst * HC);
  const float4* br = (const float4*)bias;
  float4* orow = (float4*)(out + (size_t)dst * HC);
  const float4 x0 = xr[2 * gl], x1 = xr[2 * gl + 1];
  const float4 b0 = br[2 * gl], b1 = br[2 * gl + 1];
  float4 o0, o1;
  o0.x = x0.x + b0.x + acc[0] * inv;
  o0.y = x0.y + b0.y + acc[1] * inv;
  o0.z = x0.z + b0.z + acc[2] * inv;
  o0.w = x0.w + b0.w + acc[3] * inv;
  o1.x = x1.x + b1.x + acc[4] * inv;
  o1.y = x1.y + b1.y + acc[5] * inv;
  o1.z = x1.z + b1.z + acc[6] * inv;
  o1.w = x1.w + b1.w + acc[7] * inv;
  orow[2 * gl] = o0;
  orow[2 * gl + 1] = o1;
}

extern "C" void kernel_launch(void* const* d_in, const int* in_sizes, int n_in,
                              void* d_out, int out_size, void* d_ws, size_t ws_size,
                              hipStream_t stream) {
  const float* x         = (const float*)d_in[0];
  const int*   ei        = (const int*)d_in[1];
  const float* v_mapping = (const float*)d_in[2];
  const float* W_src     = (const float*)d_in[3];
  const float* att_src   = (const float*)d_in[4];
  const float* att_dst   = (const float*)d_in[5];
  const float* bias      = (const float*)d_in[6];
  float* out = (float*)d_out;

  char* ws = (char*)d_ws;
  float*    x_proj     = (float*)ws;     ws += (size_t)N_NODES * HC * 4;  // 25.6 MB
  unsigned* xpb        = (unsigned*)ws;  ws += (size_t)N_NODES * 64 * 4;  // 12.8 MB
  float*    a_src      = (float*)ws;     ws += (size_t)N_NODES * 4;
  float*    a_dst      = (float*)ws;     ws += (size_t)N_NODES * 4;
  float*    wvec_src   = (float*)ws;     ws += 256 * 4;
  float*    wvec_dst   = (float*)ws;     ws += 256 * 4;
  int*      counts     = (int*)ws;       ws += (size_t)N_NODES * 4;
  int*      row_start  = (int*)ws;       ws += (size_t)N_NODES * 4;
  int*      gctr       = (int*)ws;       ws += 256;
  int*      rank       = (int*)ws;       ws += (size_t)E_EDGES * 4;       // 6.4 MB
  int2*     sorted     = (int2*)ws;      ws += (size_t)E_EDGES * 8;       // 12.8 MB

  k0_wvec<<<1, 256, 0, stream>>>(v_mapping, att_src, att_dst, wvec_src, wvec_dst, gctr);
  k1_node<<<(N_NODES + 63) / 64, 256, 0, stream>>>(x, W_src, wvec_src, wvec_dst,
                                                   x_proj, xpb, a_src, a_dst, counts);
  kb_hist<<<E_EDGES / 256, 256, 0, stream>>>(ei, counts, rank);
  kr_range<<<(N_NODES + 255) / 256, 256, 0, stream>>>(counts, row_start, gctr);
  kd_scatter<<<E_EDGES / 256, 256, 0, stream>>>(ei, a_src, a_dst, row_start, rank, sorted);
  ke_reduce<<<N_NODES / 16, 256, 0, stream>>>(row_start, counts, sorted,
                                              xpb, x_proj, bias, out);
}